// Round 1
// baseline (560.017 us; speedup 1.0000x reference)
//
#include <hip/hip_runtime.h>

// Problem constants
#define BB 16
#define TT 1024
#define DD 1024
#define HH 1024
#define NN 3072            // 3H
#define KK 2048            // 2D (two conv taps)
#define MM (BB * TT)       // 16384
#define TP (TT + 1)        // padded time rows in xpad (row 0 = zeros)

typedef __attribute__((ext_vector_type(8))) short short8;   // 8 x bf16
typedef __attribute__((ext_vector_type(4))) float float4v;  // MFMA acc

__device__ __forceinline__ unsigned short f2bf(float f) {
    unsigned int u = __float_as_uint(f);
    u += 0x7fffu + ((u >> 16) & 1u);   // round-to-nearest-even
    return (unsigned short)(u >> 16);
}
__device__ __forceinline__ float bf2f(unsigned short s) {
    return __uint_as_float(((unsigned int)s) << 16);
}

// async global->LDS, 16B per lane; LDS dest semantics: wave-uniform base + lane*16
__device__ __forceinline__ void gload_lds16(const unsigned short* g, unsigned short* l) {
    __builtin_amdgcn_global_load_lds(
        (const __attribute__((address_space(1))) unsigned int*)(g),
        (__attribute__((address_space(3))) unsigned int*)(l),
        16, 0, 0);
}

// ---------------- pack x: fp32 [B,T,D] -> bf16 xpad [B, T+1, D], row 0 zero ----------------
__global__ __launch_bounds__(256) void pack_x_kernel(const float* __restrict__ x,
                                                     unsigned short* __restrict__ xpad) {
    int i = blockIdx.x * 256 + threadIdx.x;          // one float4 group
    int total = BB * TP * (DD / 4);
    if (i >= total) return;
    int d4  = i & (DD / 4 - 1);
    int row = i >> 8;                                // [0, B*TP)
    int b  = row / TP;
    int tp = row - b * TP;
    float4 v = make_float4(0.f, 0.f, 0.f, 0.f);
    if (tp > 0)
        v = ((const float4*)x)[(((size_t)(b * TT + tp - 1)) << 8) + d4];
    ushort4 r4;
    r4.x = f2bf(v.x); r4.y = f2bf(v.y); r4.z = f2bf(v.z); r4.w = f2bf(v.w);
    *(ushort4*)(xpad + (((size_t)row) << 10) + (d4 << 2)) = r4;
}

// ---------------- pack w: fp32 [3H, D, 2] -> bf16 Bt [N=3072][K=2048] (B^T layout) ----------
__global__ __launch_bounds__(256) void pack_w_kernel(const float* __restrict__ w,
                                                     unsigned short* __restrict__ Bt) {
    int i = blockIdx.x * 256 + threadIdx.x;          // n*1024 + d
    if (i >= NN * DD) return;
    int n = i >> 10, d = i & 1023;
    float2 v = ((const float2*)w)[i];                // (w[n,d,0], w[n,d,1])
    Bt[(size_t)n * KK + d]       = f2bf(v.x);        // tap0 at k = d
    Bt[(size_t)n * KK + DD + d]  = f2bf(v.y);        // tap1 at k = 1024 + d
}

// ---------------- GEMM: gates = A2 * W2, fused bias + activation, bf16 out -----------------
// 128x128 tile, 256 threads (4 waves, 2x2 wave grid, 64x64 per wave = 4x4 MFMAs 16x16x32)
__global__ __launch_bounds__(256) void gemm_gates_kernel(const unsigned short* __restrict__ xpad,
                                                         const unsigned short* __restrict__ Bt,
                                                         const float* __restrict__ bias,
                                                         unsigned short* __restrict__ zfo) {
    __shared__ unsigned short As[128 * 32];
    __shared__ unsigned short Bs[128 * 32];

    const int tid  = threadIdx.x;
    const int lane = tid & 63;
    const int wave = tid >> 6;
    const int m0 = blockIdx.x * 128;
    const int n0 = blockIdx.y * 128;

    const int bidx = m0 >> 10;        // batch index (128 | 1024, so tile never straddles batch)
    const int t0   = m0 & 1023;
    const unsigned short* aBase = xpad + (((size_t)(bidx * TP + t0)) << 10);

    const int msub = (wave & 1) << 6;
    const int nsub = (wave >> 1) << 6;
    const int mrow = lane & 15;
    const int quad = lane >> 4;

    float4v acc[4][4];
#pragma unroll
    for (int i = 0; i < 4; i++)
#pragma unroll
        for (int j = 0; j < 4; j++) acc[i][j] = (float4v)0.0f;

    // per-thread staging geometry: chunk ci covers row r = ci>>2, cols (ci&3)*8 .. +7
    for (int kb = 0; kb < KK / 32; ++kb) {
        const int tap = kb >> 5;                 // 0 for k<1024, 1 for k>=1024
        const int kd0 = (kb & 31) << 5;          // k offset within tap
#pragma unroll
        for (int q = 0; q < 2; ++q) {
            int ci = q * 256 + tid;              // 0..511
            int r  = ci >> 2;
            int c8 = (ci & 3) << 3;
            // A2[m0+r, kb*32+c8 ..] = xpad[b, t0+r+tap, kd0+c8 ..]
            gload_lds16(aBase + (((size_t)(r + tap)) << 10) + kd0 + c8, As + ci * 8);
            // B^T[n0+r, kb*32+c8 ..]
            gload_lds16(Bt + (size_t)(n0 + r) * KK + (kb << 5) + c8, Bs + ci * 8);
        }
        __syncthreads();

        short8 af[4], bf[4];
#pragma unroll
        for (int i = 0; i < 4; i++) {
            af[i] = *(const short8*)(As + (msub + i * 16 + mrow) * 32 + quad * 8);
            bf[i] = *(const short8*)(Bs + (nsub + i * 16 + mrow) * 32 + quad * 8);
        }
#pragma unroll
        for (int i = 0; i < 4; i++)
#pragma unroll
            for (int j = 0; j < 4; j++)
                acc[i][j] = __builtin_amdgcn_mfma_f32_16x16x32_bf16(af[i], bf[j], acc[i][j], 0, 0, 0);
        __syncthreads();
    }

    // epilogue: bias + activation (block's n-range lies entirely within one gate)
    const bool isZ = (n0 < HH);     // tanh for Z, sigmoid for F and O
#pragma unroll
    for (int j = 0; j < 4; j++) {
        int gcol = n0 + nsub + j * 16 + mrow;
        float bv = bias[gcol];
#pragma unroll
        for (int i = 0; i < 4; i++) {
            int mbase = m0 + msub + i * 16 + quad * 4;
#pragma unroll
            for (int r = 0; r < 4; r++) {
                float v = acc[i][j][r] + bv;
                float g;
                if (isZ) {
                    float s = __builtin_amdgcn_rcpf(1.0f + __expf(-2.0f * v));
                    g = 2.0f * s - 1.0f;                     // tanh(v)
                } else {
                    g = __builtin_amdgcn_rcpf(1.0f + __expf(-v));  // sigmoid(v)
                }
                zfo[(size_t)(mbase + r) * NN + gcol] = f2bf(g);
            }
        }
    }
}

// ---------------- fo-pooling scan: c_t = f*c + (1-f)*z ; h = o*c -------------------------
__global__ __launch_bounds__(64) void scan_kernel(const unsigned short* __restrict__ zfo,
                                                  float* __restrict__ out) {
    int idx = blockIdx.x * 64 + threadIdx.x;    // 0..16383 = (b, h)
    int b  = idx >> 10;
    int hh = idx & 1023;
    const unsigned short* base = zfo + (size_t)b * TT * NN + hh;
    float* cp = out + (size_t)b * TT * HH + hh;
    float* hp = cp + (size_t)BB * TT * HH;
    float c = 0.0f;
#pragma unroll 8
    for (int t = 0; t < TT; ++t) {
        const unsigned short* p = base + (size_t)t * NN;
        float z = bf2f(p[0]);
        float f = bf2f(p[HH]);
        float o = bf2f(p[2 * HH]);
        float w = (1.0f - f) * z;     // off the dependent chain
        c = fmaf(f, c, w);            // 1 fma serial latency per step
        cp[(size_t)t << 10] = c;
        hp[(size_t)t << 10] = o * c;
    }
}

extern "C" void kernel_launch(void* const* d_in, const int* in_sizes, int n_in,
                              void* d_out, int out_size, void* d_ws, size_t ws_size,
                              hipStream_t stream) {
    const float* x    = (const float*)d_in[0];   // [B,T,D] fp32
    const float* w    = (const float*)d_in[1];   // [3H,D,2] fp32
    const float* bias = (const float*)d_in[2];   // [3H] fp32
    float* out = (float*)d_out;                  // [2, B, T, H] fp32 (c then h)

    char* ws = (char*)d_ws;
    const size_t xpad_bytes = (size_t)BB * TP * DD * 2;        // 33,587,200
    const size_t btw_bytes  = (size_t)NN * KK * 2;             // 12,582,912
    unsigned short* xpad = (unsigned short*)ws;
    unsigned short* Btw  = (unsigned short*)(ws + xpad_bytes);
    unsigned short* zfo  = (unsigned short*)(ws + xpad_bytes + btw_bytes);

    {
        int total = BB * TP * (DD / 4);
        pack_x_kernel<<<(total + 255) / 256, 256, 0, stream>>>(x, xpad);
    }
    {
        int total = NN * DD;
        pack_w_kernel<<<(total + 255) / 256, 256, 0, stream>>>(w, Btw);
    }
    {
        dim3 grid(MM / 128, NN / 128);   // 128 x 24 = 3072 blocks
        gemm_gates_kernel<<<grid, 256, 0, stream>>>(xpad, Btw, bias, zfo);
    }
    scan_kernel<<<MM / 64, 64, 0, stream>>>(zfo, out);
}

// Round 2
// 503.930 us; speedup vs baseline: 1.1113x; 1.1113x over previous
//
#include <hip/hip_runtime.h>

// Problem constants
#define BB 16
#define TT 1024
#define DD 1024
#define HH 1024
#define NN 3072            // 3H
#define KK 2048            // 2D (two conv taps)
#define MM (BB * TT)       // 16384
#define TP (TT + 1)        // padded time rows in xpad (row 0 = zeros)
#define NCH 32             // scan chunks
#define TC  32             // steps per chunk (NCH*TC == TT)

typedef __attribute__((ext_vector_type(8))) short short8;   // 8 x bf16
typedef __attribute__((ext_vector_type(4))) float float4v;  // MFMA acc

__device__ __forceinline__ unsigned short f2bf(float f) {
    unsigned int u = __float_as_uint(f);
    u += 0x7fffu + ((u >> 16) & 1u);   // round-to-nearest-even
    return (unsigned short)(u >> 16);
}
__device__ __forceinline__ float bf2f(unsigned short s) {
    return __uint_as_float(((unsigned int)s) << 16);
}

// async global->LDS, 16B per lane; LDS dest semantics: wave-uniform base + lane*16
__device__ __forceinline__ void gload_lds16(const unsigned short* g, unsigned short* l) {
    __builtin_amdgcn_global_load_lds(
        (const __attribute__((address_space(1))) unsigned int*)(g),
        (__attribute__((address_space(3))) unsigned int*)(l),
        16, 0, 0);
}

// ---------------- pack x: fp32 [B,T,D] -> bf16 xpad [B, T+1, D], row 0 zero ----------------
__global__ __launch_bounds__(256) void pack_x_kernel(const float* __restrict__ x,
                                                     unsigned short* __restrict__ xpad) {
    int i = blockIdx.x * 256 + threadIdx.x;          // one float4 group
    int total = BB * TP * (DD / 4);
    if (i >= total) return;
    int d4  = i & (DD / 4 - 1);
    int row = i >> 8;                                // [0, B*TP)
    int b  = row / TP;
    int tp = row - b * TP;
    float4 v = make_float4(0.f, 0.f, 0.f, 0.f);
    if (tp > 0)
        v = ((const float4*)x)[(((size_t)(b * TT + tp - 1)) << 8) + d4];
    ushort4 r4;
    r4.x = f2bf(v.x); r4.y = f2bf(v.y); r4.z = f2bf(v.z); r4.w = f2bf(v.w);
    *(ushort4*)(xpad + (((size_t)row) << 10) + (d4 << 2)) = r4;
}

// ---------------- pack w: fp32 [3H, D, 2] -> bf16 Bt [N=3072][K=2048] (B^T layout) ----------
__global__ __launch_bounds__(256) void pack_w_kernel(const float* __restrict__ w,
                                                     unsigned short* __restrict__ Bt) {
    int i = blockIdx.x * 256 + threadIdx.x;          // n*1024 + d
    if (i >= NN * DD) return;
    int n = i >> 10, d = i & 1023;
    float2 v = ((const float2*)w)[i];                // (w[n,d,0], w[n,d,1])
    Bt[(size_t)n * KK + d]       = f2bf(v.x);        // tap0 at k = d
    Bt[(size_t)n * KK + DD + d]  = f2bf(v.y);        // tap1 at k = 1024 + d
}

// ---------------- GEMM: gates = A2 * W2, fused bias + activation, bf16 out -----------------
// 128x128 tile, 256 threads (4 waves, 2x2 wave grid, 64x64 per wave = 4x4 MFMAs 16x16x32)
// LDS 16B-chunk column XOR-swizzled by (row>>1)&3 to break 8-way phase aliasing.
__global__ __launch_bounds__(256) void gemm_gates_kernel(const unsigned short* __restrict__ xpad,
                                                         const unsigned short* __restrict__ Bt,
                                                         const float* __restrict__ bias,
                                                         unsigned short* __restrict__ zfo) {
    __shared__ unsigned short As[128 * 32];
    __shared__ unsigned short Bs[128 * 32];

    const int tid  = threadIdx.x;
    const int lane = tid & 63;
    const int wave = tid >> 6;
    const int m0 = blockIdx.x * 128;
    const int n0 = blockIdx.y * 128;

    const int bidx = m0 >> 10;        // batch index (128 | 1024, so tile never straddles batch)
    const int t0   = m0 & 1023;
    const unsigned short* aBase = xpad + (((size_t)(bidx * TP + t0)) << 10);

    const int msub = (wave & 1) << 6;
    const int nsub = (wave >> 1) << 6;
    const int mrow = lane & 15;
    const int quad = lane >> 4;
    // swizzled chunk offset used by fragment reads (row bits 1..2 == mrow bits 1..2)
    const int csw = (quad ^ ((mrow >> 1) & 3)) << 3;

    float4v acc[4][4];
#pragma unroll
    for (int i = 0; i < 4; i++)
#pragma unroll
        for (int j = 0; j < 4; j++) acc[i][j] = (float4v)0.0f;

    // staging geometry: LDS slot ci = r*4 + cc holds global column chunk (cc ^ ((r>>1)&3))
    for (int kb = 0; kb < KK / 32; ++kb) {
        const int tap = kb >> 5;                 // 0 for k<1024, 1 for k>=1024
        const int kd0 = (kb & 31) << 5;          // k offset within tap
#pragma unroll
        for (int q = 0; q < 2; ++q) {
            int ci = q * 256 + tid;              // 0..511
            int r  = ci >> 2;
            int cs = (((ci & 3) ^ ((r >> 1) & 3)) << 3);
            gload_lds16(aBase + (((size_t)(r + tap)) << 10) + kd0 + cs, As + ci * 8);
            gload_lds16(Bt + (size_t)(n0 + r) * KK + (kb << 5) + cs, Bs + ci * 8);
        }
        __syncthreads();

        short8 af[4], bf[4];
#pragma unroll
        for (int i = 0; i < 4; i++) {
            af[i] = *(const short8*)(As + (msub + i * 16 + mrow) * 32 + csw);
            bf[i] = *(const short8*)(Bs + (nsub + i * 16 + mrow) * 32 + csw);
        }
#pragma unroll
        for (int i = 0; i < 4; i++)
#pragma unroll
            for (int j = 0; j < 4; j++)
                acc[i][j] = __builtin_amdgcn_mfma_f32_16x16x32_bf16(af[i], bf[j], acc[i][j], 0, 0, 0);
        __syncthreads();
    }

    // epilogue: bias + activation (block's n-range lies entirely within one gate)
    const bool isZ = (n0 < HH);     // tanh for Z, sigmoid for F and O
#pragma unroll
    for (int j = 0; j < 4; j++) {
        int gcol = n0 + nsub + j * 16 + mrow;
        float bv = bias[gcol];
#pragma unroll
        for (int i = 0; i < 4; i++) {
            int mbase = m0 + msub + i * 16 + quad * 4;
#pragma unroll
            for (int r = 0; r < 4; r++) {
                float v = acc[i][j][r] + bv;
                float g;
                if (isZ) {
                    float s = __builtin_amdgcn_rcpf(1.0f + __expf(-2.0f * v));
                    g = 2.0f * s - 1.0f;                     // tanh(v)
                } else {
                    g = __builtin_amdgcn_rcpf(1.0f + __expf(-v));  // sigmoid(v)
                }
                zfo[(size_t)(mbase + r) * NN + gcol] = f2bf(g);
            }
        }
    }
}

// ---------------- chunked fo-pooling scan, 3 passes ----------------------------------------
// thread g handles 2 h-channels of chunk j of chain (b,h):
//   j = g >> 13, b = (g >> 9) & 15, h = (g & 511) * 2

// Pass A: per-chunk summaries P = prod f, S = local scan from 0
__global__ __launch_bounds__(256) void scan_summary_kernel(const unsigned short* __restrict__ zfo,
                                                           float2* __restrict__ P2,
                                                           float2* __restrict__ S2) {
    int g = blockIdx.x * 256 + threadIdx.x;        // [0, 262144)
    int j = g >> 13;
    int b = (g >> 9) & 15;
    int h = (g & 511) << 1;
    const unsigned short* base = zfo + (size_t)b * TT * NN + h + (size_t)(j * TC) * NN;
    float c0 = 0.f, c1 = 0.f, p0 = 1.f, p1 = 1.f;
#pragma unroll 8
    for (int k = 0; k < TC; ++k) {
        const unsigned short* p = base + (size_t)k * NN;
        ushort2 z2 = *(const ushort2*)p;
        ushort2 f2 = *(const ushort2*)(p + HH);
        float z0 = bf2f(z2.x), z1 = bf2f(z2.y);
        float f0 = bf2f(f2.x), f1 = bf2f(f2.y);
        c0 = fmaf(f0, c0, (1.0f - f0) * z0);
        c1 = fmaf(f1, c1, (1.0f - f1) * z1);
        p0 *= f0;
        p1 *= f1;
    }
    P2[g] = make_float2(p0, p1);
    S2[g] = make_float2(c0, c1);
}

// Pass B: scan the 32 chunk summaries per chain; Cin[j] = cell state entering chunk j
__global__ __launch_bounds__(256) void scan_prefix_kernel(const float* __restrict__ P,
                                                          const float* __restrict__ S,
                                                          float* __restrict__ Cin) {
    int idx = blockIdx.x * 256 + threadIdx.x;      // [0, 16384) = (b,h)
    float c = 0.f;
#pragma unroll
    for (int j = 0; j < NCH; ++j) {
        int o = (j << 14) + idx;
        Cin[o] = c;
        c = fmaf(P[o], c, S[o]);
    }
}

// Pass C: redo local scan seeded with Cin, write c and h = o*c
__global__ __launch_bounds__(256) void scan_apply_kernel(const unsigned short* __restrict__ zfo,
                                                         const float2* __restrict__ Cin2,
                                                         float* __restrict__ out) {
    int g = blockIdx.x * 256 + threadIdx.x;        // [0, 262144)
    int j = g >> 13;
    int b = (g >> 9) & 15;
    int h = (g & 511) << 1;
    const unsigned short* base = zfo + (size_t)b * TT * NN + h + (size_t)(j * TC) * NN;
    float* cp = out + (size_t)b * TT * HH + h + (size_t)(j * TC) * HH;
    float* hp = cp + (size_t)BB * TT * HH;
    float2 ci = Cin2[g];
    float c0 = ci.x, c1 = ci.y;
#pragma unroll 8
    for (int k = 0; k < TC; ++k) {
        const unsigned short* p = base + (size_t)k * NN;
        ushort2 z2 = *(const ushort2*)p;
        ushort2 f2 = *(const ushort2*)(p + HH);
        ushort2 o2 = *(const ushort2*)(p + 2 * HH);
        float z0 = bf2f(z2.x), z1 = bf2f(z2.y);
        float f0 = bf2f(f2.x), f1 = bf2f(f2.y);
        float o0 = bf2f(o2.x), o1 = bf2f(o2.y);
        c0 = fmaf(f0, c0, (1.0f - f0) * z0);
        c1 = fmaf(f1, c1, (1.0f - f1) * z1);
        *(float2*)(cp + (size_t)k * HH) = make_float2(c0, c1);
        *(float2*)(hp + (size_t)k * HH) = make_float2(o0 * c0, o1 * c1);
    }
}

extern "C" void kernel_launch(void* const* d_in, const int* in_sizes, int n_in,
                              void* d_out, int out_size, void* d_ws, size_t ws_size,
                              hipStream_t stream) {
    const float* x    = (const float*)d_in[0];   // [B,T,D] fp32
    const float* w    = (const float*)d_in[1];   // [3H,D,2] fp32
    const float* bias = (const float*)d_in[2];   // [3H] fp32
    float* out = (float*)d_out;                  // [2, B, T, H] fp32 (c then h)

    char* ws = (char*)d_ws;
    const size_t xpad_bytes = (size_t)BB * TP * DD * 2;        // 33,587,200
    const size_t btw_bytes  = (size_t)NN * KK * 2;             // 12,582,912
    unsigned short* xpad = (unsigned short*)ws;
    unsigned short* Btw  = (unsigned short*)(ws + xpad_bytes);
    unsigned short* zfo  = (unsigned short*)(ws + xpad_bytes + btw_bytes);
    // scan scratch aliases the xpad region (dead after the GEMM): 3 x 2 MB
    float* P   = (float*)ws;
    float* S   = (float*)(ws + (size_t)MM * NCH * 4);
    float* Cin = (float*)(ws + (size_t)MM * NCH * 8);

    {
        int total = BB * TP * (DD / 4);
        pack_x_kernel<<<(total + 255) / 256, 256, 0, stream>>>(x, xpad);
    }
    {
        int total = NN * DD;
        pack_w_kernel<<<(total + 255) / 256, 256, 0, stream>>>(w, Btw);
    }
    {
        dim3 grid(MM / 128, NN / 128);   // 128 x 24 = 3072 blocks
        gemm_gates_kernel<<<grid, 256, 0, stream>>>(xpad, Btw, bias, zfo);
    }
    scan_summary_kernel<<<(MM / 2) * NCH / 256, 256, 0, stream>>>(zfo, (float2*)P, (float2*)S);
    scan_prefix_kernel<<<MM / 256, 256, 0, stream>>>(P, S, Cin);
    scan_apply_kernel<<<(MM / 2) * NCH / 256, 256, 0, stream>>>(zfo, (const float2*)Cin, out);
}

// Round 3
// 498.332 us; speedup vs baseline: 1.1238x; 1.0112x over previous
//
#include <hip/hip_runtime.h>

// Problem constants
#define BB 16
#define TT 1024
#define DD 1024
#define HH 1024
#define NN 3072            // 3H
#define KK 2048            // 2D (two conv taps)
#define MM (BB * TT)       // 16384
#define TP (TT + 1)        // padded time rows in xpad (row 0 = zeros)
#define NCH 32             // scan chunks
#define TC  32             // steps per chunk (NCH*TC == TT)
#define PLANE (1u << 24)   // 16M elements per gate plane ( = BB*HH*TT )

typedef __attribute__((ext_vector_type(8))) short short8;   // 8 x bf16
typedef __attribute__((ext_vector_type(4))) float float4v;  // MFMA acc

__device__ __forceinline__ unsigned short f2bf(float f) {
    unsigned int u = __float_as_uint(f);
    u += 0x7fffu + ((u >> 16) & 1u);   // round-to-nearest-even
    return (unsigned short)(u >> 16);
}
__device__ __forceinline__ float bf2f(unsigned short s) {
    return __uint_as_float(((unsigned int)s) << 16);
}

// async global->LDS, 16B per lane; LDS dest semantics: wave-uniform base + lane*16
__device__ __forceinline__ void gload_lds16(const unsigned short* g, unsigned short* l) {
    __builtin_amdgcn_global_load_lds(
        (const __attribute__((address_space(1))) unsigned int*)(g),
        (__attribute__((address_space(3))) unsigned int*)(l),
        16, 0, 0);
}

// ---------------- pack x: fp32 [B,T,D] -> bf16 xpad [B, T+1, D], row 0 zero ----------------
__global__ __launch_bounds__(256) void pack_x_kernel(const float* __restrict__ x,
                                                     unsigned short* __restrict__ xpad) {
    int i = blockIdx.x * 256 + threadIdx.x;          // one float4 group
    int total = BB * TP * (DD / 4);
    if (i >= total) return;
    int d4  = i & (DD / 4 - 1);
    int row = i >> 8;                                // [0, B*TP)
    int b  = row / TP;
    int tp = row - b * TP;
    float4 v = make_float4(0.f, 0.f, 0.f, 0.f);
    if (tp > 0)
        v = ((const float4*)x)[(((size_t)(b * TT + tp - 1)) << 8) + d4];
    ushort4 r4;
    r4.x = f2bf(v.x); r4.y = f2bf(v.y); r4.z = f2bf(v.z); r4.w = f2bf(v.w);
    *(ushort4*)(xpad + (((size_t)row) << 10) + (d4 << 2)) = r4;
}

// ---------------- pack w: fp32 [3H, D, 2] -> bf16 Bt [N=3072][K=2048] (B^T layout) ----------
__global__ __launch_bounds__(256) void pack_w_kernel(const float* __restrict__ w,
                                                     unsigned short* __restrict__ Bt) {
    int i = blockIdx.x * 256 + threadIdx.x;          // n*1024 + d
    if (i >= NN * DD) return;
    int n = i >> 10, d = i & 1023;
    float2 v = ((const float2*)w)[i];                // (w[n,d,0], w[n,d,1])
    Bt[(size_t)n * KK + d]       = f2bf(v.x);        // tap0 at k = d
    Bt[(size_t)n * KK + DD + d]  = f2bf(v.y);        // tap1 at k = 1024 + d
}

// ---------------- GEMM: gates = A2 * W2, fused bias + activation ---------------------------
// Output layout: zT[gate][b][h][t] bf16 (t-contiguous) via LDS-transpose epilogue.
// 128x128 tile, 256 threads (4 waves, 2x2 wave grid, 64x64 per wave = 4x4 MFMAs 16x16x32)
__global__ __launch_bounds__(256) void gemm_gates_kernel(const unsigned short* __restrict__ xpad,
                                                         const unsigned short* __restrict__ Bt,
                                                         const float* __restrict__ bias,
                                                         unsigned short* __restrict__ zT) {
    __shared__ unsigned short smem[16384];           // 32 KB: As(8KB)+Bs(8KB) then Ts(32KB)
    unsigned short* As = smem;
    unsigned short* Bs = smem + 4096;

    const int tid  = threadIdx.x;
    const int lane = tid & 63;
    const int wave = tid >> 6;
    const int m0 = blockIdx.x * 128;
    const int n0 = blockIdx.y * 128;

    const int bidx = m0 >> 10;        // batch index (128 | 1024, so tile never straddles batch)
    const int t0   = m0 & 1023;
    const unsigned short* aBase = xpad + (((size_t)(bidx * TP + t0)) << 10);

    const int msub = (wave & 1) << 6;
    const int nsub = (wave >> 1) << 6;
    const int mrow = lane & 15;
    const int quad = lane >> 4;
    // swizzled chunk offset used by fragment reads (row bits 1..2 == mrow bits 1..2)
    const int csw = (quad ^ ((mrow >> 1) & 3)) << 3;

    float4v acc[4][4];
#pragma unroll
    for (int i = 0; i < 4; i++)
#pragma unroll
        for (int j = 0; j < 4; j++) acc[i][j] = (float4v)0.0f;

    // staging geometry: LDS slot ci = r*4 + cc holds global column chunk (cc ^ ((r>>1)&3))
    for (int kb = 0; kb < KK / 32; ++kb) {
        const int tap = kb >> 5;                 // 0 for k<1024, 1 for k>=1024
        const int kd0 = (kb & 31) << 5;          // k offset within tap
#pragma unroll
        for (int q = 0; q < 2; ++q) {
            int ci = q * 256 + tid;              // 0..511
            int r  = ci >> 2;
            int cs = (((ci & 3) ^ ((r >> 1) & 3)) << 3);
            gload_lds16(aBase + (((size_t)(r + tap)) << 10) + kd0 + cs, As + ci * 8);
            gload_lds16(Bt + (size_t)(n0 + r) * KK + (kb << 5) + cs, Bs + ci * 8);
        }
        __syncthreads();

        short8 af[4], bf[4];
#pragma unroll
        for (int i = 0; i < 4; i++) {
            af[i] = *(const short8*)(As + (msub + i * 16 + mrow) * 32 + csw);
            bf[i] = *(const short8*)(Bs + (nsub + i * 16 + mrow) * 32 + csw);
        }
#pragma unroll
        for (int i = 0; i < 4; i++)
#pragma unroll
            for (int j = 0; j < 4; j++)
                acc[i][j] = __builtin_amdgcn_mfma_f32_16x16x32_bf16(af[i], bf[j], acc[i][j], 0, 0, 0);
        __syncthreads();
    }
    // After this barrier all LDS reads of As/Bs are complete; alias smem as the transpose tile.
    unsigned short* Ts = smem;    // [128 rows (n-local)][128 cols (t-local)], 16B-chunk XOR swizz

    const bool isZ = (n0 < HH);     // tanh for Z, sigmoid for F and O
#pragma unroll
    for (int j = 0; j < 4; j++) {
        int nloc = nsub + j * 16 + mrow;               // tile row (n-local)
        float bv = bias[n0 + nloc];
#pragma unroll
        for (int i = 0; i < 4; i++) {
            int mcol = msub + i * 16 + (quad << 2);    // tile col (t-local), 4 consecutive
            unsigned int d0, d1;
            {
                float v0 = acc[i][j][0] + bv, v1 = acc[i][j][1] + bv;
                float v2 = acc[i][j][2] + bv, v3 = acc[i][j][3] + bv;
                float g0, g1, g2, g3;
                if (isZ) {
                    g0 = 2.0f * __builtin_amdgcn_rcpf(1.0f + __expf(-2.0f * v0)) - 1.0f;
                    g1 = 2.0f * __builtin_amdgcn_rcpf(1.0f + __expf(-2.0f * v1)) - 1.0f;
                    g2 = 2.0f * __builtin_amdgcn_rcpf(1.0f + __expf(-2.0f * v2)) - 1.0f;
                    g3 = 2.0f * __builtin_amdgcn_rcpf(1.0f + __expf(-2.0f * v3)) - 1.0f;
                } else {
                    g0 = __builtin_amdgcn_rcpf(1.0f + __expf(-v0));
                    g1 = __builtin_amdgcn_rcpf(1.0f + __expf(-v1));
                    g2 = __builtin_amdgcn_rcpf(1.0f + __expf(-v2));
                    g3 = __builtin_amdgcn_rcpf(1.0f + __expf(-v3));
                }
                d0 = (unsigned int)f2bf(g0) | ((unsigned int)f2bf(g1) << 16);
                d1 = (unsigned int)f2bf(g2) | ((unsigned int)f2bf(g3) << 16);
            }
            int chunk = (mcol >> 3) ^ (nloc & 7);      // XOR-swizzle 16B chunk within row
            int el = nloc * 128 + (chunk << 3) + (mcol & 7);
            *(uint2*)(Ts + el) = make_uint2(d0, d1);   // 8B store, aligned
        }
    }
    __syncthreads();

    // coalesced store: row np = n-local, 16 lanes x 16B cover 128 t
    const int rl = tid & 15;
    const int rg = tid >> 4;
    const int gate = n0 >> 10;
    unsigned short* plane = zT + ((size_t)gate << 24);
#pragma unroll
    for (int p = 0; p < 8; p++) {
        int np = (p << 4) + rg;
        int lchunk = rl ^ (np & 7);
        short8 vv = *(const short8*)(Ts + np * 128 + (lchunk << 3));
        int h = (n0 & 1023) + np;
        size_t dst = ((((size_t)((bidx << 10) | h)) << 10) | (unsigned)(t0 + (rl << 3)));
        *(short8*)(plane + dst) = vv;
    }
}

// ---------------- chunked fo-pooling scan, 3 passes ----------------------------------------
// thread g: h = g & 1023, b = (g>>10)&15, chunk j = g>>14.  summaries at o = (j<<14)|(b<<10)|h

// Pass A: per-chunk summaries P = prod f, S = local scan from 0 (t-contiguous 16B loads)
__global__ __launch_bounds__(256) void scan_summary_kernel(const unsigned short* __restrict__ zT,
                                                           float* __restrict__ P,
                                                           float* __restrict__ S) {
    int g = blockIdx.x * 256 + threadIdx.x;        // [0, 524288)
    int h = g & 1023;
    int b = (g >> 10) & 15;
    int j = g >> 14;
    const unsigned short* zp = zT + ((((size_t)((b << 10) | h)) << 10) + j * TC);
    const unsigned short* fp = zp + PLANE;
    short8 zv[4], fv[4];
#pragma unroll
    for (int q = 0; q < 4; ++q) {
        zv[q] = *(const short8*)(zp + q * 8);
        fv[q] = *(const short8*)(fp + q * 8);
    }
    float c = 0.f, pr = 1.f;
#pragma unroll
    for (int q = 0; q < 4; ++q)
#pragma unroll
        for (int k = 0; k < 8; ++k) {
            float z = bf2f((unsigned short)zv[q][k]);
            float f = bf2f((unsigned short)fv[q][k]);
            c = fmaf(f, c, (1.0f - f) * z);
            pr *= f;
        }
    int o = (j << 14) | (b << 10) | h;
    P[o] = pr;
    S[o] = c;
}

// Pass B: scan the 32 chunk summaries per chain; Cin[j] = cell state entering chunk j
__global__ __launch_bounds__(256) void scan_prefix_kernel(const float* __restrict__ P,
                                                          const float* __restrict__ S,
                                                          float* __restrict__ Cin) {
    int idx = blockIdx.x * 256 + threadIdx.x;      // [0, 16384) = (b,h)
    float c = 0.f;
#pragma unroll
    for (int j = 0; j < NCH; ++j) {
        int o = (j << 14) + idx;
        Cin[o] = c;
        c = fmaf(P[o], c, S[o]);
    }
}

// Pass C: redo local scan seeded with Cin, write c and h = o*c (coalesced fp32 stores)
__global__ __launch_bounds__(256) void scan_apply_kernel(const unsigned short* __restrict__ zT,
                                                         const float* __restrict__ Cin,
                                                         float* __restrict__ out) {
    int g = blockIdx.x * 256 + threadIdx.x;        // [0, 524288)
    int h = g & 1023;
    int b = (g >> 10) & 15;
    int j = g >> 14;
    const unsigned short* zp = zT + ((((size_t)((b << 10) | h)) << 10) + j * TC);
    const unsigned short* fp = zp + PLANE;
    const unsigned short* op = zp + 2 * (size_t)PLANE;
    short8 zv[4], fv[4], ov[4];
#pragma unroll
    for (int q = 0; q < 4; ++q) {
        zv[q] = *(const short8*)(zp + q * 8);
        fv[q] = *(const short8*)(fp + q * 8);
        ov[q] = *(const short8*)(op + q * 8);
    }
    float c = Cin[(j << 14) | (b << 10) | h];
    float* cbase = out + ((((size_t)((b << 10) | (j * TC))) << 10) | h);
#pragma unroll
    for (int q = 0; q < 4; ++q)
#pragma unroll
        for (int k = 0; k < 8; ++k) {
            float z = bf2f((unsigned short)zv[q][k]);
            float f = bf2f((unsigned short)fv[q][k]);
            float o = bf2f((unsigned short)ov[q][k]);
            c = fmaf(f, c, (1.0f - f) * z);
            float* cp = cbase + (((size_t)(q * 8 + k)) << 10);
            cp[0] = c;
            cp[(size_t)1 << 24] = o * c;           // h-plane offset = BB*TT*HH
        }
}

extern "C" void kernel_launch(void* const* d_in, const int* in_sizes, int n_in,
                              void* d_out, int out_size, void* d_ws, size_t ws_size,
                              hipStream_t stream) {
    const float* x    = (const float*)d_in[0];   // [B,T,D] fp32
    const float* w    = (const float*)d_in[1];   // [3H,D,2] fp32
    const float* bias = (const float*)d_in[2];   // [3H] fp32
    float* out = (float*)d_out;                  // [2, B, T, H] fp32 (c then h)

    char* ws = (char*)d_ws;
    const size_t xpad_bytes = (size_t)BB * TP * DD * 2;        // 33,587,200
    const size_t btw_bytes  = (size_t)NN * KK * 2;             // 12,582,912
    unsigned short* xpad = (unsigned short*)ws;
    unsigned short* Btw  = (unsigned short*)(ws + xpad_bytes);
    unsigned short* zT   = (unsigned short*)(ws + xpad_bytes + btw_bytes);   // [3][B][H][T]
    // scan scratch aliases the xpad region (dead after the GEMM): 3 x 2 MB
    float* P   = (float*)ws;
    float* S   = (float*)(ws + (size_t)MM * NCH * 4);
    float* Cin = (float*)(ws + (size_t)MM * NCH * 8);

    {
        int total = BB * TP * (DD / 4);
        pack_x_kernel<<<(total + 255) / 256, 256, 0, stream>>>(x, xpad);
    }
    {
        int total = NN * DD;
        pack_w_kernel<<<(total + 255) / 256, 256, 0, stream>>>(w, Btw);
    }
    {
        dim3 grid(MM / 128, NN / 128);   // 128 x 24 = 3072 blocks
        gemm_gates_kernel<<<grid, 256, 0, stream>>>(xpad, Btw, bias, zT);
    }
    scan_summary_kernel<<<MM * NCH / 256, 256, 0, stream>>>(zT, P, S);
    scan_prefix_kernel<<<MM / 256, 256, 0, stream>>>(P, S, Cin);
    scan_apply_kernel<<<MM * NCH / 256, 256, 0, stream>>>(zT, Cin, out);
}